// Round 1
// baseline (5583.736 us; speedup 1.0000x reference)
//
#include <hip/hip_runtime.h>
#include <stdint.h>

typedef uint16_t u16;
typedef uint32_t u32;
typedef uint64_t u64;
typedef short short8 __attribute__((ext_vector_type(8)));
typedef float f32x4 __attribute__((ext_vector_type(4)));

#define DEV static __device__ __forceinline__

DEV u16 f2bf(float f){
  u32 x = __builtin_bit_cast(u32, f);
  return (u16)((x + 0x7fffu + ((x >> 16) & 1u)) >> 16);
}

DEV f32x4 mfma16(short8 a, short8 b, f32x4 c){
  return __builtin_amdgcn_mfma_f32_16x16x32_bf16(a, b, c, 0, 0, 0);
}

// ---------------------------------------------------------------- embedding
__global__ __launch_bounds__(256)
void embed_kernel(const int* __restrict__ tid, const int* __restrict__ sid,
                  const float* __restrict__ tok, const float* __restrict__ pos,
                  const float* __restrict__ seg,
                  float* __restrict__ x, u16* __restrict__ xb)
{
  const int row = blockIdx.x;          // b*512 + s
  const int s = row & 511;
  const int tk = tid[row], sg = sid[row];
  const int t = threadIdx.x;
#pragma unroll
  for (int e = 0; e < 3; ++e){
    int i = t + e*256;
    float v = tok[(u64)tk*768 + i] + seg[(u64)sg*768 + i] + pos[(u64)s*768 + i];
    x[(u64)row*768 + i] = v;
    xb[(u64)row*768 + i] = f2bf(v);
  }
}

// ---------------------------------------------------------------- fp32 -> bf16
__global__ __launch_bounds__(256)
void cvt_bf16(const float4* __restrict__ in, ushort4* __restrict__ out, int n4)
{
  int i = blockIdx.x*256 + threadIdx.x;
  if (i >= n4) return;
  float4 f = in[i];
  ushort4 o;
  o.x = f2bf(f.x); o.y = f2bf(f.y); o.z = f2bf(f.z); o.w = f2bf(f.w);
  out[i] = o;
}

// ---------------------------------------------------------------- GEMM: C = A[M,K] @ W[N,K]^T + bias
// EPI: 0 = fp32 store, 1 = bf16 store, 2 = bf16 store with exact GELU
template<int EPI>
__global__ __launch_bounds__(256)
void gemm_bt(const u16* __restrict__ A, const u16* __restrict__ W,
             const float* __restrict__ bias, void* __restrict__ Cout,
             int M, int N, int K)
{
  __shared__ u16 As[128*40];
  __shared__ u16 Ws[128*40];
  const int t  = threadIdx.x;
  const int w  = t >> 6, ll = t & 63;
  const int lr = ll & 15, lg = ll >> 4;
  const int bm = blockIdx.y, bn = blockIdx.x;
  const int wm = (w >> 1)*64, wn = (w & 1)*64;
  const int ldl = 40;

  f32x4 acc[4][4] = {};

  const int srow = t >> 2;              // 0..63
  const int scol = (t & 3)*8;           // 0,8,16,24
  int rA0 = bm*128 + srow;       if (rA0 > M-1) rA0 = M-1;
  int rA1 = bm*128 + srow + 64;  if (rA1 > M-1) rA1 = M-1;
  int rW0 = bn*128 + srow;       if (rW0 > N-1) rW0 = N-1;
  int rW1 = bn*128 + srow + 64;  if (rW1 > N-1) rW1 = N-1;

  for (int k0 = 0; k0 < K; k0 += 32){
    short8 a0 = *(const short8*)(A + (u64)rA0*K + k0 + scol);
    short8 a1 = *(const short8*)(A + (u64)rA1*K + k0 + scol);
    short8 w0 = *(const short8*)(W + (u64)rW0*K + k0 + scol);
    short8 w1 = *(const short8*)(W + (u64)rW1*K + k0 + scol);
    __syncthreads();
    *(short8*)(As + srow*ldl + scol)        = a0;
    *(short8*)(As + (srow + 64)*ldl + scol) = a1;
    *(short8*)(Ws + srow*ldl + scol)        = w0;
    *(short8*)(Ws + (srow + 64)*ldl + scol) = w1;
    __syncthreads();
    short8 af[4], wf[4];
#pragma unroll
    for (int mi = 0; mi < 4; ++mi)
      af[mi] = *(const short8*)(As + (wm + mi*16 + lr)*ldl + 8*lg);
#pragma unroll
    for (int ni = 0; ni < 4; ++ni)
      wf[ni] = *(const short8*)(Ws + (wn + ni*16 + lr)*ldl + 8*lg);
#pragma unroll
    for (int mi = 0; mi < 4; ++mi)
#pragma unroll
      for (int ni = 0; ni < 4; ++ni)
        acc[mi][ni] = mfma16(af[mi], wf[ni], acc[mi][ni]);
  }

#pragma unroll
  for (int ni = 0; ni < 4; ++ni){
    int col = bn*128 + wn + ni*16 + lr;
    if (col >= N) continue;
    float bv = bias ? bias[col] : 0.f;
#pragma unroll
    for (int mi = 0; mi < 4; ++mi){
#pragma unroll
      for (int r = 0; r < 4; ++r){
        int row = bm*128 + wm + mi*16 + lg*4 + r;
        if (row >= M) continue;
        float v = acc[mi][ni][r] + bv;
        if constexpr (EPI == 2) v = 0.5f*v*(1.0f + erff(v*0.70710678118f));
        if constexpr (EPI == 0) ((float*)Cout)[(u64)row*N + col] = v;
        else                    ((u16*)Cout)[(u64)row*N + col] = f2bf(v);
      }
    }
  }
}

// ---------------------------------------------------------------- V transpose: [b,s,h,d] -> vT[(b,h,d), s]
__global__ __launch_bounds__(256)
void transpose_v(const u16* __restrict__ vb, u16* __restrict__ vt)
{
  __shared__ u16 tile[64][72];
  const int st = blockIdx.x, h = blockIdx.y, b = blockIdx.z;
  const int t = threadIdx.x;
#pragma unroll
  for (int e = 0; e < 2; ++e){
    int lin = t + e*256;
    int s = lin >> 3, c8 = (lin & 7)*8;
    *(short8*)(&tile[s][c8]) =
        *(const short8*)(vb + (u64)(b*512 + st*64 + s)*768 + h*64 + c8);
  }
  __syncthreads();
#pragma unroll
  for (int e = 0; e < 2; ++e){
    int lin = t + e*256;
    int d = lin >> 3, s8 = (lin & 7)*8;
    short8 ov;
#pragma unroll
    for (int i = 0; i < 8; ++i) ov[i] = (short)tile[s8 + i][d];
    *(short8*)(vt + ((u64)(b*12 + h)*64 + d)*512 + st*64 + s8) = ov;
  }
}

// ---------------------------------------------------------------- flash attention
__global__ __launch_bounds__(256)
void attn_kernel(const u16* __restrict__ qb, const u16* __restrict__ kb,
                 const u16* __restrict__ vt, u16* __restrict__ ob)
{
  __shared__ u16 p_lds[4][16][72];
  const int t = threadIdx.x, w = t >> 6, ll = t & 63;
  const int lr = ll & 15, lg = ll >> 4;
  const int qt = blockIdx.x, h = blockIdx.y, b = blockIdx.z;
  const int q0 = qt*64 + w*16;

  const u16* qrow = qb + (u64)(b*512 + q0 + lr)*768 + h*64 + 8*lg;
  const short8 qf0 = *(const short8*)qrow;
  const short8 qf1 = *(const short8*)(qrow + 32);

  const u16* kbh = kb + (u64)(b*512)*768 + h*64;
  const u16* vth = vt + (u64)(b*12 + h)*64*512;

  float m_r[4], l_r[4];
  f32x4 o_acc[4] = {};
#pragma unroll
  for (int r = 0; r < 4; ++r){ m_r[r] = -1e30f; l_r[r] = 0.f; }

  for (int jt = 0; jt < 8; ++jt){
    const int jb = jt*64;
    f32x4 s[4] = {};
#pragma unroll
    for (int jn = 0; jn < 4; ++jn){
      const u16* kr = kbh + (u64)(jb + jn*16 + lr)*768 + 8*lg;
      short8 kf0 = *(const short8*)kr;
      short8 kf1 = *(const short8*)(kr + 32);
      s[jn] = mfma16(qf0, kf0, s[jn]);
      s[jn] = mfma16(qf1, kf1, s[jn]);
    }
#pragma unroll
    for (int jn = 0; jn < 4; ++jn)
#pragma unroll
      for (int r = 0; r < 4; ++r) s[jn][r] *= 0.125f;

    float mn[4], corr[4], rs[4];
#pragma unroll
    for (int r = 0; r < 4; ++r){
      float v = fmaxf(fmaxf(s[0][r], s[1][r]), fmaxf(s[2][r], s[3][r]));
#pragma unroll
      for (int m = 1; m < 16; m <<= 1) v = fmaxf(v, __shfl_xor(v, m));
      mn[r] = fmaxf(m_r[r], v);
      corr[r] = __expf(m_r[r] - mn[r]);
      m_r[r] = mn[r];
      rs[r] = 0.f;
    }
#pragma unroll
    for (int jn = 0; jn < 4; ++jn)
#pragma unroll
      for (int r = 0; r < 4; ++r){
        float pv = __expf(s[jn][r] - mn[r]);
        s[jn][r] = pv;
        rs[r] += pv;
      }
#pragma unroll
    for (int r = 0; r < 4; ++r){
      float v = rs[r];
#pragma unroll
      for (int m = 1; m < 16; m <<= 1) v += __shfl_xor(v, m);
      l_r[r] = l_r[r]*corr[r] + v;
    }
#pragma unroll
    for (int nd = 0; nd < 4; ++nd)
#pragma unroll
      for (int r = 0; r < 4; ++r) o_acc[nd][r] *= corr[r];

#pragma unroll
    for (int jn = 0; jn < 4; ++jn)
#pragma unroll
      for (int r = 0; r < 4; ++r)
        p_lds[w][4*lg + r][jn*16 + lr] = f2bf(s[jn][r]);
    __syncthreads();
    short8 pa0 = *(const short8*)(&p_lds[w][lr][8*lg]);
    short8 pa1 = *(const short8*)(&p_lds[w][lr][32 + 8*lg]);
#pragma unroll
    for (int nd = 0; nd < 4; ++nd){
      const u16* vr = vth + (u64)(nd*16 + lr)*512 + jb + 8*lg;
      short8 vf0 = *(const short8*)vr;
      short8 vf1 = *(const short8*)(vr + 32);
      o_acc[nd] = mfma16(pa0, vf0, o_acc[nd]);
      o_acc[nd] = mfma16(pa1, vf1, o_acc[nd]);
    }
    __syncthreads();
  }
#pragma unroll
  for (int r = 0; r < 4; ++r) l_r[r] = 1.f / l_r[r];
#pragma unroll
  for (int nd = 0; nd < 4; ++nd)
#pragma unroll
    for (int r = 0; r < 4; ++r)
      ob[(u64)(b*512 + q0 + 4*lg + r)*768 + h*64 + nd*16 + lr] =
          f2bf(o_acc[nd][r]*l_r[r]);
}

// ---------------------------------------------------------------- residual + LayerNorm
__global__ __launch_bounds__(256)
void ln_res(const float* xin, const float* __restrict__ yin,
            const float* __restrict__ g, const float* __restrict__ be,
            float* xout, u16* __restrict__ xbout)
{
  __shared__ float sred[8];
  const int row = blockIdx.x, t = threadIdx.x;
  const int w = t >> 6, ll = t & 63;
  float v[3]; float s = 0.f, sq = 0.f;
#pragma unroll
  for (int e = 0; e < 3; ++e){
    int i = t + e*256;
    float val = xin[(u64)row*768 + i] + yin[(u64)row*768 + i];
    v[e] = val; s += val; sq += val*val;
  }
#pragma unroll
  for (int m = 1; m < 64; m <<= 1){ s += __shfl_xor(s, m); sq += __shfl_xor(sq, m); }
  if (ll == 0){ sred[w] = s; sred[4 + w] = sq; }
  __syncthreads();
  s  = sred[0] + sred[1] + sred[2] + sred[3];
  sq = sred[4] + sred[5] + sred[6] + sred[7];
  const float mean = s*(1.f/768.f);
  const float rstd = rsqrtf(sq*(1.f/768.f) - mean*mean + 1e-5f);
#pragma unroll
  for (int e = 0; e < 3; ++e){
    int i = t + e*256;
    float o = (v[e] - mean)*rstd*g[i] + be[i];
    xout[(u64)row*768 + i] = o;
    xbout[(u64)row*768 + i] = f2bf(o);
  }
}

// ---------------------------------------------------------------- gather masked rows
__global__ __launch_bounds__(256)
void gather_rows(const u16* __restrict__ xb, const int* __restrict__ mids,
                 u16* __restrict__ xg)
{
  const int row = blockIdx.x;      // b*77 + i
  const int b = row / 77;
  const int src = b*512 + mids[row];
  const int t = threadIdx.x;
#pragma unroll
  for (int e = 0; e < 3; ++e){
    int i = t + e*256;
    xg[(u64)row*768 + i] = xb[(u64)src*768 + i];
  }
}

// ---------------------------------------------------------------- host
extern "C" void kernel_launch(void* const* d_in, const int* in_sizes, int n_in,
                              void* d_out, int out_size, void* d_ws, size_t ws_size,
                              hipStream_t stream)
{
  const int*   token_ids  = (const int*)  d_in[0];
  const int*   segment_ids= (const int*)  d_in[1];
  const int*   mask_ids   = (const int*)  d_in[2];
  const float* tok_emb    = (const float*)d_in[3];
  const float* pos_emb    = (const float*)d_in[4];
  const float* seg_emb    = (const float*)d_in[5];
  const float* dense_w    = (const float*)d_in[6];
  const float* dense_b    = (const float*)d_in[7];
  const float* Wq = (const float*)d_in[8];  const float* bq = (const float*)d_in[9];
  const float* Wk = (const float*)d_in[10]; const float* bk = (const float*)d_in[11];
  const float* Wv = (const float*)d_in[12]; const float* bv = (const float*)d_in[13];
  const float* Wo = (const float*)d_in[14]; const float* bo = (const float*)d_in[15];
  const float* W1 = (const float*)d_in[16]; const float* b1 = (const float*)d_in[17];
  const float* W2 = (const float*)d_in[18]; const float* b2 = (const float*)d_in[19];
  const float* g1 = (const float*)d_in[20]; const float* be1= (const float*)d_in[21];
  const float* g2 = (const float*)d_in[22]; const float* be2= (const float*)d_in[23];

  char* p = (char*)d_ws;
  auto alloc = [&](size_t bytes)->char*{
    char* r = p; p += (bytes + 255) & ~(size_t)255; return r;
  };
  const u64 T = 8192;
  float* x    = (float*)alloc(T*768*4);
  float* y    = (float*)alloc(T*768*4);
  u16*   xb   = (u16*)  alloc(T*768*2);
  u16*   qb   = (u16*)  alloc(T*768*2);
  u16*   kb   = (u16*)  alloc(T*768*2);
  u16*   vb   = (u16*)  alloc(T*768*2);
  u16*   vT   = (u16*)  alloc(T*768*2);
  u16*   obuf = (u16*)  alloc(T*768*2);
  u16*   h1b  = (u16*)  alloc(T*3072*2);
  u16*   xg   = (u16*)  alloc((u64)1232*768*2);
  u16*   wqb  = (u16*)  alloc((u64)768*768*2);
  u16*   wkb  = (u16*)  alloc((u64)768*768*2);
  u16*   wvb  = (u16*)  alloc((u64)768*768*2);
  u16*   wob  = (u16*)  alloc((u64)768*768*2);
  u16*   w1b  = (u16*)  alloc((u64)3072*768*2);
  u16*   w2b  = (u16*)  alloc((u64)3072*768*2);
  u16*   dwb  = h1b;   // reuse (dense_w bf16 = 46.9 MB <= h1b 50.3 MB)

  if ((size_t)(p - (char*)d_ws) > ws_size) return;  // ws too small -> loud failure

  embed_kernel<<<dim3(8192), dim3(256), 0, stream>>>(
      token_ids, segment_ids, tok_emb, pos_emb, seg_emb, x, xb);

  for (int l = 0; l < 12; ++l){
    cvt_bf16<<<dim3(576),  dim3(256), 0, stream>>>((const float4*)(Wq + (u64)l*589824), (ushort4*)wqb, 147456);
    cvt_bf16<<<dim3(576),  dim3(256), 0, stream>>>((const float4*)(Wk + (u64)l*589824), (ushort4*)wkb, 147456);
    cvt_bf16<<<dim3(576),  dim3(256), 0, stream>>>((const float4*)(Wv + (u64)l*589824), (ushort4*)wvb, 147456);
    cvt_bf16<<<dim3(576),  dim3(256), 0, stream>>>((const float4*)(Wo + (u64)l*589824), (ushort4*)wob, 147456);
    cvt_bf16<<<dim3(2304), dim3(256), 0, stream>>>((const float4*)(W1 + (u64)l*2359296), (ushort4*)w1b, 589824);
    cvt_bf16<<<dim3(2304), dim3(256), 0, stream>>>((const float4*)(W2 + (u64)l*2359296), (ushort4*)w2b, 589824);

    gemm_bt<1><<<dim3(6, 64), dim3(256), 0, stream>>>(xb, wqb, bq + (u64)l*768, qb, 8192, 768, 768);
    gemm_bt<1><<<dim3(6, 64), dim3(256), 0, stream>>>(xb, wkb, bk + (u64)l*768, kb, 8192, 768, 768);
    gemm_bt<1><<<dim3(6, 64), dim3(256), 0, stream>>>(xb, wvb, bv + (u64)l*768, vb, 8192, 768, 768);

    transpose_v<<<dim3(8, 12, 16), dim3(256), 0, stream>>>(vb, vT);
    attn_kernel<<<dim3(8, 12, 16), dim3(256), 0, stream>>>(qb, kb, vT, obuf);

    gemm_bt<0><<<dim3(6, 64), dim3(256), 0, stream>>>(obuf, wob, bo + (u64)l*768, y, 8192, 768, 768);
    ln_res<<<dim3(8192), dim3(256), 0, stream>>>(x, y, g1 + (u64)l*768, be1 + (u64)l*768, x, xb);

    gemm_bt<2><<<dim3(24, 64), dim3(256), 0, stream>>>(xb, w1b, b1 + (u64)l*3072, h1b, 8192, 3072, 768);
    gemm_bt<0><<<dim3(6, 64), dim3(256), 0, stream>>>(h1b, w2b, b2 + (u64)l*768, y, 8192, 768, 3072);
    ln_res<<<dim3(8192), dim3(256), 0, stream>>>(x, y, g2 + (u64)l*768, be2 + (u64)l*768, x, xb);
  }

  gather_rows<<<dim3(1232), dim3(256), 0, stream>>>(xb, mask_ids, xg);
  cvt_bf16<<<dim3(22892), dim3(256), 0, stream>>>((const float4*)dense_w, (ushort4*)dwb, 5860224);
  gemm_bt<0><<<dim3(239, 10), dim3(256), 0, stream>>>(xg, dwb, dense_b, (float*)d_out, 1232, 30522, 768);
}

// Round 2
// 5350.317 us; speedup vs baseline: 1.0436x; 1.0436x over previous
//
#include <hip/hip_runtime.h>
#include <stdint.h>

typedef uint16_t u16;
typedef uint32_t u32;
typedef uint64_t u64;
typedef short short8 __attribute__((ext_vector_type(8)));
typedef float f32x4 __attribute__((ext_vector_type(4)));

#define DEV static __device__ __forceinline__

DEV u16 f2bf(float f){
  u32 x = __builtin_bit_cast(u32, f);
  return (u16)((x + 0x7fffu + ((x >> 16) & 1u)) >> 16);
}

DEV f32x4 mfma16(short8 a, short8 b, f32x4 c){
  return __builtin_amdgcn_mfma_f32_16x16x32_bf16(a, b, c, 0, 0, 0);
}

DEV void async16(const void* g, void* l){
  __builtin_amdgcn_global_load_lds(
      (const __attribute__((address_space(1))) u32*)g,
      (__attribute__((address_space(3))) u32*)l, 16, 0, 0);
}

// ---------------------------------------------------------------- embedding
__global__ __launch_bounds__(256)
void embed_kernel(const int* __restrict__ tid, const int* __restrict__ sid,
                  const float* __restrict__ tok, const float* __restrict__ pos,
                  const float* __restrict__ seg,
                  float* __restrict__ x, u16* __restrict__ xb)
{
  const int row = blockIdx.x;          // b*512 + s
  const int s = row & 511;
  const int tk = tid[row], sg = sid[row];
  const int t = threadIdx.x;
#pragma unroll
  for (int e = 0; e < 3; ++e){
    int i = t + e*256;
    float v = tok[(u64)tk*768 + i] + seg[(u64)sg*768 + i] + pos[(u64)s*768 + i];
    x[(u64)row*768 + i] = v;
    xb[(u64)row*768 + i] = f2bf(v);
  }
}

// ---------------------------------------------------------------- fp32 -> bf16
__global__ __launch_bounds__(256)
void cvt_bf16(const float4* __restrict__ in, ushort4* __restrict__ out, int n4)
{
  int i = blockIdx.x*256 + threadIdx.x;
  if (i >= n4) return;
  float4 f = in[i];
  ushort4 o;
  o.x = f2bf(f.x); o.y = f2bf(f.y); o.z = f2bf(f.z); o.w = f2bf(f.w);
  out[i] = o;
}

// ---------------------------------------------------------------- bias concat (Q,K,V) for all layers
__global__ __launch_bounds__(256)
void concat_bias(const float* __restrict__ bq, const float* __restrict__ bk,
                 const float* __restrict__ bv, float* __restrict__ out)
{
  const int l = blockIdx.x;     // 12
  const int t = threadIdx.x;    // 256
#pragma unroll
  for (int e = 0; e < 3; ++e){
    int i = t + e*256;
    out[(u64)l*2304 + i]        = bq[(u64)l*768 + i];
    out[(u64)l*2304 + 768 + i]  = bk[(u64)l*768 + i];
    out[(u64)l*2304 + 1536 + i] = bv[(u64)l*768 + i];
  }
}

// ---------------------------------------------------------------- GEMM (m97 structure):
// C = A[M,K] @ W[N,K]^T + bias, bf16 inputs. 128x128 tile, BK=32, 4 waves,
// global_load_lds width-16 staging into linear LDS, bijective XCD-chunked swizzle.
// EPI: 0 = fp32 store, 1 = bf16 store, 2 = bf16 store with exact GELU
template<int EPI>
__global__ __launch_bounds__(256)
void gemm_m97(const u16* __restrict__ A, const u16* __restrict__ W,
              const float* __restrict__ bias, void* __restrict__ Cout,
              int M, int N, int K, int GM)
{
  __shared__ u16 As[128*32];
  __shared__ u16 Ws[128*32];
  const int t = threadIdx.x;
  const int w = t >> 6, l = t & 63;
  const int lr = l & 15, lg = l >> 4;

  // bijective chunked XCD swizzle (m204): consecutive wgid land on same XCD
  const int nwg = gridDim.x;
  const int orig = blockIdx.x;
  const int q = nwg >> 3, r = nwg & 7;
  const int xcd = orig & 7, slot = orig >> 3;
  const int wgid = (xcd < r ? xcd*(q+1) : r*(q+1) + (xcd-r)*q) + slot;
  const int bm = wgid % GM, bn = wgid / GM;   // bm-fast: consecutive tiles share W panel

  // staging descriptors: wave w owns LDS chunks 4w..4w+3 (each 1 KiB = 16 rows)
  const u16* srcp[4];
  u16* ldsp[4];
#pragma unroll
  for (int i = 0; i < 4; ++i){
    int c = w*4 + i;                       // 0..15
    int rt = (c & 7)*16 + (l >> 2);        // row within 128-row tile
    int col = (l & 3)*8;                   // k-offset (u16)
    if (c < 8){
      int row = bm*128 + rt; if (row > M-1) row = M-1;
      srcp[i] = A + (u64)row*K + col;
      ldsp[i] = As + c*512 + l*8;
    } else {
      int row = bn*128 + rt; if (row > N-1) row = N-1;
      srcp[i] = W + (u64)row*K + col;
      ldsp[i] = Ws + (c - 8)*512 + l*8;
    }
  }

  const int wm = (w >> 1)*64, wn = (w & 1)*64;
  f32x4 acc[4][4] = {};

  for (int k0 = 0; k0 < K; k0 += 32){
    __syncthreads();                       // previous tile fully consumed
#pragma unroll
    for (int i = 0; i < 4; ++i) async16(srcp[i] + k0, ldsp[i]);
    __syncthreads();                       // vmcnt drained -> LDS valid

    short8 af[4], wf[4];
#pragma unroll
    for (int mi = 0; mi < 4; ++mi)
      af[mi] = *(const short8*)(As + (wm + mi*16 + lr)*32 + lg*8);
#pragma unroll
    for (int ni = 0; ni < 4; ++ni)
      wf[ni] = *(const short8*)(Ws + (wn + ni*16 + lr)*32 + lg*8);
#pragma unroll
    for (int mi = 0; mi < 4; ++mi)
#pragma unroll
      for (int ni = 0; ni < 4; ++ni)
        acc[mi][ni] = mfma16(af[mi], wf[ni], acc[mi][ni]);
  }

#pragma unroll
  for (int ni = 0; ni < 4; ++ni){
    int col = bn*128 + wn + ni*16 + lr;
    if (col >= N) continue;
    float bv = bias ? bias[col] : 0.f;
#pragma unroll
    for (int mi = 0; mi < 4; ++mi){
#pragma unroll
      for (int rr = 0; rr < 4; ++rr){
        int row = bm*128 + wm + mi*16 + lg*4 + rr;
        if (row >= M) continue;
        float v = acc[mi][ni][rr] + bv;
        if constexpr (EPI == 2) v = 0.5f*v*(1.0f + erff(v*0.70710678118f));
        if constexpr (EPI == 0) ((float*)Cout)[(u64)row*N + col] = v;
        else                    ((u16*)Cout)[(u64)row*N + col] = f2bf(v);
      }
    }
  }
}

// ---------------------------------------------------------------- V transpose: qkv[b,s,(2304)] V part -> vT[(b,h,d), s]
__global__ __launch_bounds__(256)
void transpose_v(const u16* __restrict__ qkv, u16* __restrict__ vt)
{
  __shared__ u16 tile[64][72];
  const int st = blockIdx.x, h = blockIdx.y, b = blockIdx.z;
  const int t = threadIdx.x;
#pragma unroll
  for (int e = 0; e < 2; ++e){
    int lin = t + e*256;
    int s = lin >> 3, c8 = (lin & 7)*8;
    *(short8*)(&tile[s][c8]) =
        *(const short8*)(qkv + (u64)(b*512 + st*64 + s)*2304 + 1536 + h*64 + c8);
  }
  __syncthreads();
#pragma unroll
  for (int e = 0; e < 2; ++e){
    int lin = t + e*256;
    int d = lin >> 3, s8 = (lin & 7)*8;
    short8 ov;
#pragma unroll
    for (int i = 0; i < 8; ++i) ov[i] = (short)tile[s8 + i][d];
    *(short8*)(vt + ((u64)(b*12 + h)*64 + d)*512 + st*64 + s8) = ov;
  }
}

// ---------------------------------------------------------------- flash attention (reads fused qkv buffer)
__global__ __launch_bounds__(256)
void attn_kernel(const u16* __restrict__ qkv, const u16* __restrict__ vt,
                 u16* __restrict__ ob)
{
  __shared__ u16 p_lds[4][16][72];
  const int t = threadIdx.x, w = t >> 6, ll = t & 63;
  const int lr = ll & 15, lg = ll >> 4;
  const int qt = blockIdx.x, h = blockIdx.y, b = blockIdx.z;
  const int q0 = qt*64 + w*16;

  const u16* qrow = qkv + (u64)(b*512 + q0 + lr)*2304 + h*64 + 8*lg;
  const short8 qf0 = *(const short8*)qrow;
  const short8 qf1 = *(const short8*)(qrow + 32);

  const u16* kbh = qkv + (u64)(b*512)*2304 + 768 + h*64;
  const u16* vth = vt + (u64)(b*12 + h)*64*512;

  float m_r[4], l_r[4];
  f32x4 o_acc[4] = {};
#pragma unroll
  for (int r = 0; r < 4; ++r){ m_r[r] = -1e30f; l_r[r] = 0.f; }

  for (int jt = 0; jt < 8; ++jt){
    const int jb = jt*64;
    f32x4 s[4] = {};
#pragma unroll
    for (int jn = 0; jn < 4; ++jn){
      const u16* kr = kbh + (u64)(jb + jn*16 + lr)*2304 + 8*lg;
      short8 kf0 = *(const short8*)kr;
      short8 kf1 = *(const short8*)(kr + 32);
      s[jn] = mfma16(qf0, kf0, s[jn]);
      s[jn] = mfma16(qf1, kf1, s[jn]);
    }
#pragma unroll
    for (int jn = 0; jn < 4; ++jn)
#pragma unroll
      for (int r = 0; r < 4; ++r) s[jn][r] *= 0.125f;

    float mn[4], corr[4], rs[4];
#pragma unroll
    for (int r = 0; r < 4; ++r){
      float v = fmaxf(fmaxf(s[0][r], s[1][r]), fmaxf(s[2][r], s[3][r]));
#pragma unroll
      for (int m = 1; m < 16; m <<= 1) v = fmaxf(v, __shfl_xor(v, m));
      mn[r] = fmaxf(m_r[r], v);
      corr[r] = __expf(m_r[r] - mn[r]);
      m_r[r] = mn[r];
      rs[r] = 0.f;
    }
#pragma unroll
    for (int jn = 0; jn < 4; ++jn)
#pragma unroll
      for (int r = 0; r < 4; ++r){
        float pv = __expf(s[jn][r] - mn[r]);
        s[jn][r] = pv;
        rs[r] += pv;
      }
#pragma unroll
    for (int r = 0; r < 4; ++r){
      float v = rs[r];
#pragma unroll
      for (int m = 1; m < 16; m <<= 1) v += __shfl_xor(v, m);
      l_r[r] = l_r[r]*corr[r] + v;
    }
#pragma unroll
    for (int nd = 0; nd < 4; ++nd)
#pragma unroll
      for (int r = 0; r < 4; ++r) o_acc[nd][r] *= corr[r];

#pragma unroll
    for (int jn = 0; jn < 4; ++jn)
#pragma unroll
      for (int r = 0; r < 4; ++r)
        p_lds[w][4*lg + r][jn*16 + lr] = f2bf(s[jn][r]);
    __syncthreads();
    short8 pa0 = *(const short8*)(&p_lds[w][lr][8*lg]);
    short8 pa1 = *(const short8*)(&p_lds[w][lr][32 + 8*lg]);
#pragma unroll
    for (int nd = 0; nd < 4; ++nd){
      const u16* vr = vth + (u64)(nd*16 + lr)*512 + jb + 8*lg;
      short8 vf0 = *(const short8*)vr;
      short8 vf1 = *(const short8*)(vr + 32);
      o_acc[nd] = mfma16(pa0, vf0, o_acc[nd]);
      o_acc[nd] = mfma16(pa1, vf1, o_acc[nd]);
    }
    __syncthreads();
  }
#pragma unroll
  for (int r = 0; r < 4; ++r) l_r[r] = 1.f / l_r[r];
#pragma unroll
  for (int nd = 0; nd < 4; ++nd)
#pragma unroll
    for (int r = 0; r < 4; ++r)
      ob[(u64)(b*512 + q0 + 4*lg + r)*768 + h*64 + nd*16 + lr] =
          f2bf(o_acc[nd][r]*l_r[r]);
}

// ---------------------------------------------------------------- residual + LayerNorm
__global__ __launch_bounds__(256)
void ln_res(const float* xin, const float* __restrict__ yin,
            const float* __restrict__ g, const float* __restrict__ be,
            float* xout, u16* __restrict__ xbout)
{
  __shared__ float sred[8];
  const int row = blockIdx.x, t = threadIdx.x;
  const int w = t >> 6, ll = t & 63;
  float v[3]; float s = 0.f, sq = 0.f;
#pragma unroll
  for (int e = 0; e < 3; ++e){
    int i = t + e*256;
    float val = xin[(u64)row*768 + i] + yin[(u64)row*768 + i];
    v[e] = val; s += val; sq += val*val;
  }
#pragma unroll
  for (int m = 1; m < 64; m <<= 1){ s += __shfl_xor(s, m); sq += __shfl_xor(sq, m); }
  if (ll == 0){ sred[w] = s; sred[4 + w] = sq; }
  __syncthreads();
  s  = sred[0] + sred[1] + sred[2] + sred[3];
  sq = sred[4] + sred[5] + sred[6] + sred[7];
  const float mean = s*(1.f/768.f);
  const float rstd = rsqrtf(sq*(1.f/768.f) - mean*mean + 1e-5f);
#pragma unroll
  for (int e = 0; e < 3; ++e){
    int i = t + e*256;
    float o = (v[e] - mean)*rstd*g[i] + be[i];
    xout[(u64)row*768 + i] = o;
    xbout[(u64)row*768 + i] = f2bf(o);
  }
}

// ---------------------------------------------------------------- gather masked rows
__global__ __launch_bounds__(256)
void gather_rows(const u16* __restrict__ xb, const int* __restrict__ mids,
                 u16* __restrict__ xg)
{
  const int row = blockIdx.x;      // b*77 + i
  const int b = row / 77;
  const int src = b*512 + mids[row];
  const int t = threadIdx.x;
#pragma unroll
  for (int e = 0; e < 3; ++e){
    int i = t + e*256;
    xg[(u64)row*768 + i] = xb[(u64)src*768 + i];
  }
}

// ---------------------------------------------------------------- host
extern "C" void kernel_launch(void* const* d_in, const int* in_sizes, int n_in,
                              void* d_out, int out_size, void* d_ws, size_t ws_size,
                              hipStream_t stream)
{
  const int*   token_ids  = (const int*)  d_in[0];
  const int*   segment_ids= (const int*)  d_in[1];
  const int*   mask_ids   = (const int*)  d_in[2];
  const float* tok_emb    = (const float*)d_in[3];
  const float* pos_emb    = (const float*)d_in[4];
  const float* seg_emb    = (const float*)d_in[5];
  const float* dense_w    = (const float*)d_in[6];
  const float* dense_b    = (const float*)d_in[7];
  const float* Wq = (const float*)d_in[8];  const float* bq = (const float*)d_in[9];
  const float* Wk = (const float*)d_in[10]; const float* bk = (const float*)d_in[11];
  const float* Wv = (const float*)d_in[12]; const float* bv = (const float*)d_in[13];
  const float* Wo = (const float*)d_in[14]; const float* bo = (const float*)d_in[15];
  const float* W1 = (const float*)d_in[16]; const float* b1 = (const float*)d_in[17];
  const float* W2 = (const float*)d_in[18]; const float* b2 = (const float*)d_in[19];
  const float* g1 = (const float*)d_in[20]; const float* be1= (const float*)d_in[21];
  const float* g2 = (const float*)d_in[22]; const float* be2= (const float*)d_in[23];

  char* p = (char*)d_ws;
  auto alloc = [&](size_t bytes)->char*{
    char* r = p; p += (bytes + 255) & ~(size_t)255; return r;
  };
  const u64 T = 8192;
  float* x    = (float*)alloc(T*768*4);
  float* y    = (float*)alloc(T*768*4);
  u16*   xb   = (u16*)  alloc(T*768*2);
  u16*   qkvb = (u16*)  alloc(T*2304*2);
  u16*   vT   = (u16*)  alloc(T*768*2);
  u16*   obuf = (u16*)  alloc(T*768*2);
  u16*   h1b  = (u16*)  alloc(T*3072*2);
  u16*   xg   = (u16*)  alloc((u64)1232*768*2);
  u16*   wqkv = (u16*)  alloc((u64)2304*768*2);
  u16*   wob  = (u16*)  alloc((u64)768*768*2);
  u16*   w1b  = (u16*)  alloc((u64)3072*768*2);
  u16*   w2b  = (u16*)  alloc((u64)3072*768*2);
  float* bqkv = (float*)alloc((u64)12*2304*4);
  u16*   dwb  = h1b;   // reuse (dense_w bf16 = 46.9 MB <= h1b 50.3 MB)

  if ((size_t)(p - (char*)d_ws) > ws_size) return;  // ws too small -> loud failure

  embed_kernel<<<dim3(8192), dim3(256), 0, stream>>>(
      token_ids, segment_ids, tok_emb, pos_emb, seg_emb, x, xb);
  concat_bias<<<dim3(12), dim3(256), 0, stream>>>(bq, bk, bv, bqkv);

  for (int l = 0; l < 12; ++l){
    cvt_bf16<<<dim3(576),  dim3(256), 0, stream>>>((const float4*)(Wq + (u64)l*589824), (ushort4*)(wqkv),            147456);
    cvt_bf16<<<dim3(576),  dim3(256), 0, stream>>>((const float4*)(Wk + (u64)l*589824), (ushort4*)(wqkv + 589824),   147456);
    cvt_bf16<<<dim3(576),  dim3(256), 0, stream>>>((const float4*)(Wv + (u64)l*589824), (ushort4*)(wqkv + 1179648),  147456);
    cvt_bf16<<<dim3(576),  dim3(256), 0, stream>>>((const float4*)(Wo + (u64)l*589824), (ushort4*)wob, 147456);
    cvt_bf16<<<dim3(2304), dim3(256), 0, stream>>>((const float4*)(W1 + (u64)l*2359296), (ushort4*)w1b, 589824);
    cvt_bf16<<<dim3(2304), dim3(256), 0, stream>>>((const float4*)(W2 + (u64)l*2359296), (ushort4*)w2b, 589824);

    gemm_m97<1><<<dim3(18*64), dim3(256), 0, stream>>>(xb, wqkv, bqkv + (u64)l*2304, qkvb, 8192, 2304, 768, 64);

    transpose_v<<<dim3(8, 12, 16), dim3(256), 0, stream>>>(qkvb, vT);
    attn_kernel<<<dim3(8, 12, 16), dim3(256), 0, stream>>>(qkvb, vT, obuf);

    gemm_m97<0><<<dim3(6*64), dim3(256), 0, stream>>>(obuf, wob, bo + (u64)l*768, y, 8192, 768, 768, 64);
    ln_res<<<dim3(8192), dim3(256), 0, stream>>>(x, y, g1 + (u64)l*768, be1 + (u64)l*768, x, xb);

    gemm_m97<2><<<dim3(24*64), dim3(256), 0, stream>>>(xb, w1b, b1 + (u64)l*3072, h1b, 8192, 3072, 768, 64);
    gemm_m97<0><<<dim3(6*64), dim3(256), 0, stream>>>(h1b, w2b, b2 + (u64)l*768, y, 8192, 768, 3072, 64);
    ln_res<<<dim3(8192), dim3(256), 0, stream>>>(x, y, g2 + (u64)l*768, be2 + (u64)l*768, x, xb);
  }

  gather_rows<<<dim3(1232), dim3(256), 0, stream>>>(xb, mask_ids, xg);
  cvt_bf16<<<dim3(22892), dim3(256), 0, stream>>>((const float4*)dense_w, (ushort4*)dwb, 5860224);
  gemm_m97<0><<<dim3(239*10), dim3(256), 0, stream>>>(xg, dwb, dense_b, (float*)d_out, 1232, 30522, 768, 10);
}

// Round 3
// 4449.318 us; speedup vs baseline: 1.2550x; 1.2025x over previous
//
#include <hip/hip_runtime.h>
#include <stdint.h>

typedef uint16_t u16;
typedef uint32_t u32;
typedef uint64_t u64;
typedef short short8 __attribute__((ext_vector_type(8)));
typedef float f32x4 __attribute__((ext_vector_type(4)));

#define DEV static __device__ __forceinline__

DEV u16 f2bf(float f){
  u32 x = __builtin_bit_cast(u32, f);
  return (u16)((x + 0x7fffu + ((x >> 16) & 1u)) >> 16);
}

DEV f32x4 mfma16(short8 a, short8 b, f32x4 c){
  return __builtin_amdgcn_mfma_f32_16x16x32_bf16(a, b, c, 0, 0, 0);
}

DEV void async16(const void* g, void* l){
  __builtin_amdgcn_global_load_lds(
      (const __attribute__((address_space(1))) u32*)g,
      (__attribute__((address_space(3))) u32*)l, 16, 0, 0);
}

// ---------------------------------------------------------------- embedding
__global__ __launch_bounds__(256)
void embed_kernel(const int* __restrict__ tid, const int* __restrict__ sid,
                  const float* __restrict__ tok, const float* __restrict__ pos,
                  const float* __restrict__ seg,
                  float* __restrict__ x, u16* __restrict__ xb)
{
  const int row = blockIdx.x;          // b*512 + s
  const int s = row & 511;
  const int tk = tid[row], sg = sid[row];
  const int t = threadIdx.x;
#pragma unroll
  for (int e = 0; e < 3; ++e){
    int i = t + e*256;
    float v = tok[(u64)tk*768 + i] + seg[(u64)sg*768 + i] + pos[(u64)s*768 + i];
    x[(u64)row*768 + i] = v;
    xb[(u64)row*768 + i] = f2bf(v);
  }
}

// ---------------------------------------------------------------- fp32 -> bf16
__global__ __launch_bounds__(256)
void cvt_bf16(const float4* __restrict__ in, ushort4* __restrict__ out, int n4)
{
  int i = blockIdx.x*256 + threadIdx.x;
  if (i >= n4) return;
  float4 f = in[i];
  ushort4 o;
  o.x = f2bf(f.x); o.y = f2bf(f.y); o.z = f2bf(f.z); o.w = f2bf(f.w);
  out[i] = o;
}

// ---------------------------------------------------------------- bias concat (Q,K,V) for all layers
__global__ __launch_bounds__(256)
void concat_bias(const float* __restrict__ bq, const float* __restrict__ bk,
                 const float* __restrict__ bv, float* __restrict__ out)
{
  const int l = blockIdx.x;     // 12
  const int t = threadIdx.x;    // 256
#pragma unroll
  for (int e = 0; e < 3; ++e){
    int i = t + e*256;
    out[(u64)l*2304 + i]        = bq[(u64)l*768 + i];
    out[(u64)l*2304 + 768 + i]  = bk[(u64)l*768 + i];
    out[(u64)l*2304 + 1536 + i] = bv[(u64)l*768 + i];
  }
}

// ---------------------------------------------------------------- GEMM:
// C = A[M,K] @ W[N,K]^T + bias, bf16 in. 128x128 tile, BK=32, 4 waves.
// Double-buffered global_load_lds staging (stage next || compute cur, one
// barrier/K-step), bijective XCD-chunked swizzle, LDS-staged coalesced epilogue.
// EPI: 0 = fp32 store, 1 = bf16 store, 2 = bf16 store with exact GELU
template<int EPI>
__global__ __launch_bounds__(256)
void gemm_db(const u16* __restrict__ A, const u16* __restrict__ W,
             const float* __restrict__ bias, void* __restrict__ Cout,
             int M, int N, int K, int GM)
{
  __shared__ u16 As[2][128*32];
  __shared__ u16 Ws[2][128*32];
  __shared__ float ep[4][16*68];        // per-wave epilogue staging
  const int t = threadIdx.x;
  const int w = t >> 6, l = t & 63;
  const int lr = l & 15, lg = l >> 4;

  // bijective chunked XCD swizzle (m204)
  const int nwg = gridDim.x;
  const int orig = blockIdx.x;
  const int q = nwg >> 3, r = nwg & 7;
  const int xcd = orig & 7, slot = orig >> 3;
  const int wgid = (xcd < r ? xcd*(q+1) : r*(q+1) + (xcd-r)*q) + slot;
  const int bm = wgid % GM, bn = wgid / GM;   // bm-fast: consecutive tiles share W panel

  // staging descriptors: wave w owns LDS chunks 4w..4w+3 (each 1 KiB = 16 rows)
  const u16* srcp[4];
  u16* ldsp[4];
#pragma unroll
  for (int i = 0; i < 4; ++i){
    int c = w*4 + i;                       // 0..15
    int rt = (c & 7)*16 + (l >> 2);        // row within 128-row tile
    int col = (l & 3)*8;                   // k-offset (u16)
    if (c < 8){
      int row = bm*128 + rt; if (row > M-1) row = M-1;
      srcp[i] = A + (u64)row*K + col;
      ldsp[i] = &As[0][c*512 + l*8];
    } else {
      int row = bn*128 + rt; if (row > N-1) row = N-1;
      srcp[i] = W + (u64)row*K + col;
      ldsp[i] = &Ws[0][(c - 8)*512 + l*8];
    }
  }

  const int wm = (w >> 1)*64, wn = (w & 1)*64;
  f32x4 acc[4][4] = {};

  const int nt = K >> 5;
  int buf = 0;
  // prologue: stage tile 0
#pragma unroll
  for (int i = 0; i < 4; ++i) async16(srcp[i], ldsp[i]);
  __syncthreads();

  for (int kt = 0; kt < nt; ++kt){
    if (kt + 1 < nt){
      const int k0 = (kt + 1) << 5;
#pragma unroll
      for (int i = 0; i < 4; ++i) async16(srcp[i] + k0, ldsp[i] + (buf ^ 1)*4096);
    }
    short8 af[4], wf[4];
#pragma unroll
    for (int mi = 0; mi < 4; ++mi)
      af[mi] = *(const short8*)(&As[buf][(wm + mi*16 + lr)*32 + lg*8]);
#pragma unroll
    for (int ni = 0; ni < 4; ++ni)
      wf[ni] = *(const short8*)(&Ws[buf][(wn + ni*16 + lr)*32 + lg*8]);
#pragma unroll
    for (int mi = 0; mi < 4; ++mi)
#pragma unroll
      for (int ni = 0; ni < 4; ++ni)
        acc[mi][ni] = mfma16(af[mi], wf[ni], acc[mi][ni]);
    if (kt + 1 < nt){
      __syncthreads();                     // drains prefetch vmcnt + guards dbuf reuse
      buf ^= 1;
    }
  }

  // ---- LDS-staged coalesced epilogue (per-wave region, no barriers) ----
  constexpr int EPLD = 68;
  float* epw = &ep[w][0];
#pragma unroll
  for (int mi = 0; mi < 4; ++mi){
#pragma unroll
    for (int ni = 0; ni < 4; ++ni){
      int col = bn*128 + wn + ni*16 + lr;
      float bv = bias ? bias[col < N ? col : N-1] : 0.f;
#pragma unroll
      for (int rr = 0; rr < 4; ++rr){
        float v = acc[mi][ni][rr] + bv;
        if constexpr (EPI == 2) v = 0.5f*v*(1.0f + erff(v*0.70710678118f));
        epw[(lg*4 + rr)*EPLD + ni*16 + lr] = v;
      }
    }
    asm volatile("s_waitcnt lgkmcnt(0)" ::: "memory");
    if constexpr (EPI == 0){
#pragma unroll
      for (int ps = 0; ps < 4; ++ps){
        int rloc = ps*4 + (l >> 4);
        int row = bm*128 + wm + mi*16 + rloc;
        int col = bn*128 + wn + (l & 15)*4;
        f32x4 v4 = *(const f32x4*)&epw[rloc*EPLD + (l & 15)*4];
        if (row < M){
          if (col + 3 < N) *(f32x4*)((float*)Cout + (u64)row*N + col) = v4;
          else {
#pragma unroll
            for (int j = 0; j < 4; ++j)
              if (col + j < N) ((float*)Cout)[(u64)row*N + col + j] = v4[j];
          }
        }
      }
    } else {
#pragma unroll
      for (int ps = 0; ps < 2; ++ps){
        int rloc = ps*8 + (l >> 3);
        int row = bm*128 + wm + mi*16 + rloc;
        int col = bn*128 + wn + (l & 7)*8;
        f32x4 a4 = *(const f32x4*)&epw[rloc*EPLD + (l & 7)*8];
        f32x4 b4 = *(const f32x4*)&epw[rloc*EPLD + (l & 7)*8 + 4];
        short8 o8;
        o8[0] = f2bf(a4[0]); o8[1] = f2bf(a4[1]); o8[2] = f2bf(a4[2]); o8[3] = f2bf(a4[3]);
        o8[4] = f2bf(b4[0]); o8[5] = f2bf(b4[1]); o8[6] = f2bf(b4[2]); o8[7] = f2bf(b4[3]);
        if (row < M){
          if (col + 7 < N) *(short8*)((u16*)Cout + (u64)row*N + col) = o8;
          else {
#pragma unroll
            for (int j = 0; j < 8; ++j)
              if (col + j < N) ((u16*)Cout)[(u64)row*N + col + j] = (u16)o8[j];
          }
        }
      }
    }
    asm volatile("s_waitcnt lgkmcnt(0)" ::: "memory");  // epw reads done before next mi
  }
}

// ---------------------------------------------------------------- V transpose: qkv[b,s,(2304)] V part -> vT[(b,h,d), s]
__global__ __launch_bounds__(256)
void transpose_v(const u16* __restrict__ qkv, u16* __restrict__ vt)
{
  __shared__ u16 tile[64][72];
  const int st = blockIdx.x, h = blockIdx.y, b = blockIdx.z;
  const int t = threadIdx.x;
#pragma unroll
  for (int e = 0; e < 2; ++e){
    int lin = t + e*256;
    int s = lin >> 3, c8 = (lin & 7)*8;
    *(short8*)(&tile[s][c8]) =
        *(const short8*)(qkv + (u64)(b*512 + st*64 + s)*2304 + 1536 + h*64 + c8);
  }
  __syncthreads();
#pragma unroll
  for (int e = 0; e < 2; ++e){
    int lin = t + e*256;
    int d = lin >> 3, s8 = (lin & 7)*8;
    short8 ov;
#pragma unroll
    for (int i = 0; i < 8; ++i) ov[i] = (short)tile[s8 + i][d];
    *(short8*)(vt + ((u64)(b*12 + h)*64 + d)*512 + st*64 + s8) = ov;
  }
}

// ---------------------------------------------------------------- flash attention (reads fused qkv buffer)
__global__ __launch_bounds__(256)
void attn_kernel(const u16* __restrict__ qkv, const u16* __restrict__ vt,
                 u16* __restrict__ ob)
{
  __shared__ u16 p_lds[4][16][72];
  const int t = threadIdx.x, w = t >> 6, ll = t & 63;
  const int lr = ll & 15, lg = ll >> 4;
  const int qt = blockIdx.x, h = blockIdx.y, b = blockIdx.z;
  const int q0 = qt*64 + w*16;

  const u16* qrow = qkv + (u64)(b*512 + q0 + lr)*2304 + h*64 + 8*lg;
  const short8 qf0 = *(const short8*)qrow;
  const short8 qf1 = *(const short8*)(qrow + 32);

  const u16* kbh = qkv + (u64)(b*512)*2304 + 768 + h*64;
  const u16* vth = vt + (u64)(b*12 + h)*64*512;

  float m_r[4], l_r[4];
  f32x4 o_acc[4] = {};
#pragma unroll
  for (int r = 0; r < 4; ++r){ m_r[r] = -1e30f; l_r[r] = 0.f; }

  for (int jt = 0; jt < 8; ++jt){
    const int jb = jt*64;
    f32x4 s[4] = {};
#pragma unroll
    for (int jn = 0; jn < 4; ++jn){
      const u16* kr = kbh + (u64)(jb + jn*16 + lr)*2304 + 8*lg;
      short8 kf0 = *(const short8*)kr;
      short8 kf1 = *(const short8*)(kr + 32);
      s[jn] = mfma16(qf0, kf0, s[jn]);
      s[jn] = mfma16(qf1, kf1, s[jn]);
    }
#pragma unroll
    for (int jn = 0; jn < 4; ++jn)
#pragma unroll
      for (int r = 0; r < 4; ++r) s[jn][r] *= 0.125f;

    float mn[4], corr[4], rs[4];
#pragma unroll
    for (int r = 0; r < 4; ++r){
      float v = fmaxf(fmaxf(s[0][r], s[1][r]), fmaxf(s[2][r], s[3][r]));
#pragma unroll
      for (int m = 1; m < 16; m <<= 1) v = fmaxf(v, __shfl_xor(v, m));
      mn[r] = fmaxf(m_r[r], v);
      corr[r] = __expf(m_r[r] - mn[r]);
      m_r[r] = mn[r];
      rs[r] = 0.f;
    }
#pragma unroll
    for (int jn = 0; jn < 4; ++jn)
#pragma unroll
      for (int r = 0; r < 4; ++r){
        float pv = __expf(s[jn][r] - mn[r]);
        s[jn][r] = pv;
        rs[r] += pv;
      }
#pragma unroll
    for (int r = 0; r < 4; ++r){
      float v = rs[r];
#pragma unroll
      for (int m = 1; m < 16; m <<= 1) v += __shfl_xor(v, m);
      l_r[r] = l_r[r]*corr[r] + v;
    }
#pragma unroll
    for (int nd = 0; nd < 4; ++nd)
#pragma unroll
      for (int r = 0; r < 4; ++r) o_acc[nd][r] *= corr[r];

#pragma unroll
    for (int jn = 0; jn < 4; ++jn)
#pragma unroll
      for (int r = 0; r < 4; ++r)
        p_lds[w][4*lg + r][jn*16 + lr] = f2bf(s[jn][r]);
    __syncthreads();
    short8 pa0 = *(const short8*)(&p_lds[w][lr][8*lg]);
    short8 pa1 = *(const short8*)(&p_lds[w][lr][32 + 8*lg]);
#pragma unroll
    for (int nd = 0; nd < 4; ++nd){
      const u16* vr = vth + (u64)(nd*16 + lr)*512 + jb + 8*lg;
      short8 vf0 = *(const short8*)vr;
      short8 vf1 = *(const short8*)(vr + 32);
      o_acc[nd] = mfma16(pa0, vf0, o_acc[nd]);
      o_acc[nd] = mfma16(pa1, vf1, o_acc[nd]);
    }
    __syncthreads();
  }
#pragma unroll
  for (int r = 0; r < 4; ++r) l_r[r] = 1.f / l_r[r];
  // coalesced output via p_lds (free after final barrier)
#pragma unroll
  for (int nd = 0; nd < 4; ++nd)
#pragma unroll
    for (int r = 0; r < 4; ++r)
      p_lds[w][4*lg + r][nd*16 + lr] = f2bf(o_acc[nd][r]*l_r[r]);
  asm volatile("s_waitcnt lgkmcnt(0)" ::: "memory");
#pragma unroll
  for (int ps = 0; ps < 2; ++ps){
    int row = ps*8 + (ll >> 3);
    short8 ov = *(const short8*)(&p_lds[w][row][(ll & 7)*8]);
    *(short8*)(ob + (u64)(b*512 + q0 + row)*768 + h*64 + (ll & 7)*8) = ov;
  }
}

// ---------------------------------------------------------------- residual + LayerNorm
__global__ __launch_bounds__(256)
void ln_res(const float* xin, const float* __restrict__ yin,
            const float* __restrict__ g, const float* __restrict__ be,
            float* xout, u16* __restrict__ xbout)
{
  __shared__ float sred[8];
  const int row = blockIdx.x, t = threadIdx.x;
  const int w = t >> 6, ll = t & 63;
  float v[3]; float s = 0.f, sq = 0.f;
#pragma unroll
  for (int e = 0; e < 3; ++e){
    int i = t + e*256;
    float val = xin[(u64)row*768 + i] + yin[(u64)row*768 + i];
    v[e] = val; s += val; sq += val*val;
  }
#pragma unroll
  for (int m = 1; m < 64; m <<= 1){ s += __shfl_xor(s, m); sq += __shfl_xor(sq, m); }
  if (ll == 0){ sred[w] = s; sred[4 + w] = sq; }
  __syncthreads();
  s  = sred[0] + sred[1] + sred[2] + sred[3];
  sq = sred[4] + sred[5] + sred[6] + sred[7];
  const float mean = s*(1.f/768.f);
  const float rstd = rsqrtf(sq*(1.f/768.f) - mean*mean + 1e-5f);
#pragma unroll
  for (int e = 0; e < 3; ++e){
    int i = t + e*256;
    float o = (v[e] - mean)*rstd*g[i] + be[i];
    xout[(u64)row*768 + i] = o;
    xbout[(u64)row*768 + i] = f2bf(o);
  }
}

// ---------------------------------------------------------------- gather masked rows
__global__ __launch_bounds__(256)
void gather_rows(const u16* __restrict__ xb, const int* __restrict__ mids,
                 u16* __restrict__ xg)
{
  const int row = blockIdx.x;      // b*77 + i
  const int b = row / 77;
  const int src = b*512 + mids[row];
  const int t = threadIdx.x;
#pragma unroll
  for (int e = 0; e < 3; ++e){
    int i = t + e*256;
    xg[(u64)row*768 + i] = xb[(u64)src*768 + i];
  }
}

// ---------------------------------------------------------------- host
extern "C" void kernel_launch(void* const* d_in, const int* in_sizes, int n_in,
                              void* d_out, int out_size, void* d_ws, size_t ws_size,
                              hipStream_t stream)
{
  const int*   token_ids  = (const int*)  d_in[0];
  const int*   segment_ids= (const int*)  d_in[1];
  const int*   mask_ids   = (const int*)  d_in[2];
  const float* tok_emb    = (const float*)d_in[3];
  const float* pos_emb    = (const float*)d_in[4];
  const float* seg_emb    = (const float*)d_in[5];
  const float* dense_w    = (const float*)d_in[6];
  const float* dense_b    = (const float*)d_in[7];
  const float* Wq = (const float*)d_in[8];  const float* bq = (const float*)d_in[9];
  const float* Wk = (const float*)d_in[10]; const float* bk = (const float*)d_in[11];
  const float* Wv = (const float*)d_in[12]; const float* bv = (const float*)d_in[13];
  const float* Wo = (const float*)d_in[14]; const float* bo = (const float*)d_in[15];
  const float* W1 = (const float*)d_in[16]; const float* b1 = (const float*)d_in[17];
  const float* W2 = (const float*)d_in[18]; const float* b2 = (const float*)d_in[19];
  const float* g1 = (const float*)d_in[20]; const float* be1= (const float*)d_in[21];
  const float* g2 = (const float*)d_in[22]; const float* be2= (const float*)d_in[23];

  char* p = (char*)d_ws;
  auto alloc = [&](size_t bytes)->char*{
    char* r = p; p += (bytes + 255) & ~(size_t)255; return r;
  };
  const u64 T = 8192;
  float* x    = (float*)alloc(T*768*4);
  float* y    = (float*)alloc(T*768*4);
  u16*   xb   = (u16*)  alloc(T*768*2);
  u16*   qkvb = (u16*)  alloc(T*2304*2);
  u16*   vT   = (u16*)  alloc(T*768*2);
  u16*   obuf = (u16*)  alloc(T*768*2);
  u16*   h1b  = (u16*)  alloc(T*3072*2);
  u16*   xg   = (u16*)  alloc((u64)1232*768*2);
  u16*   wqkv = (u16*)  alloc((u64)2304*768*2);
  u16*   wob  = (u16*)  alloc((u64)768*768*2);
  u16*   w1b  = (u16*)  alloc((u64)3072*768*2);
  u16*   w2b  = (u16*)  alloc((u64)3072*768*2);
  float* bqkv = (float*)alloc((u64)12*2304*4);
  u16*   dwb  = h1b;   // reuse (dense_w bf16 = 46.9 MB <= h1b 50.3 MB)

  if ((size_t)(p - (char*)d_ws) > ws_size) return;  // ws too small -> loud failure

  embed_kernel<<<dim3(8192), dim3(256), 0, stream>>>(
      token_ids, segment_ids, tok_emb, pos_emb, seg_emb, x, xb);
  concat_bias<<<dim3(12), dim3(256), 0, stream>>>(bq, bk, bv, bqkv);

  for (int l = 0; l < 12; ++l){
    cvt_bf16<<<dim3(576),  dim3(256), 0, stream>>>((const float4*)(Wq + (u64)l*589824), (ushort4*)(wqkv),            147456);
    cvt_bf16<<<dim3(576),  dim3(256), 0, stream>>>((const float4*)(Wk + (u64)l*589824), (ushort4*)(wqkv + 589824),   147456);
    cvt_bf16<<<dim3(576),  dim3(256), 0, stream>>>((const float4*)(Wv + (u64)l*589824), (ushort4*)(wqkv + 1179648),  147456);
    cvt_bf16<<<dim3(576),  dim3(256), 0, stream>>>((const float4*)(Wo + (u64)l*589824), (ushort4*)wob, 147456);
    cvt_bf16<<<dim3(2304), dim3(256), 0, stream>>>((const float4*)(W1 + (u64)l*2359296), (ushort4*)w1b, 589824);
    cvt_bf16<<<dim3(2304), dim3(256), 0, stream>>>((const float4*)(W2 + (u64)l*2359296), (ushort4*)w2b, 589824);

    gemm_db<1><<<dim3(18*64), dim3(256), 0, stream>>>(xb, wqkv, bqkv + (u64)l*2304, qkvb, 8192, 2304, 768, 64);

    transpose_v<<<dim3(8, 12, 16), dim3(256), 0, stream>>>(qkvb, vT);
    attn_kernel<<<dim3(8, 12, 16), dim3(256), 0, stream>>>(qkvb, vT, obuf);

    gemm_db<0><<<dim3(6*64), dim3(256), 0, stream>>>(obuf, wob, bo + (u64)l*768, y, 8192, 768, 768, 64);
    ln_res<<<dim3(8192), dim3(256), 0, stream>>>(x, y, g1 + (u64)l*768, be1 + (u64)l*768, x, xb);

    gemm_db<2><<<dim3(24*64), dim3(256), 0, stream>>>(xb, w1b, b1 + (u64)l*3072, h1b, 8192, 3072, 768, 64);
    gemm_db<0><<<dim3(6*64), dim3(256), 0, stream>>>(h1b, w2b, b2 + (u64)l*768, y, 8192, 768, 3072, 64);
    ln_res<<<dim3(8192), dim3(256), 0, stream>>>(x, y, g2 + (u64)l*768, be2 + (u64)l*768, x, xb);
  }

  gather_rows<<<dim3(1232), dim3(256), 0, stream>>>(xb, mask_ids, xg);
  cvt_bf16<<<dim3(22892), dim3(256), 0, stream>>>((const float4*)dense_w, (ushort4*)dwb, 5860224);
  gemm_db<0><<<dim3(239*10), dim3(256), 0, stream>>>(xg, dwb, dense_b, (float*)d_out, 1232, 30522, 768, 10);
}